// Round 5
// baseline (198.385 us; speedup 1.0000x reference)
//
#include <hip/hip_runtime.h>

#define G_    48
#define NPG_  128
#define NTOT_ 6144
#define D_    128
#define EPG_  4096
#define ETOT_ 196608

// element offsets into f32 d_out
#define OUT_ADJ  0ull
#define OUT_PERT 37748736ull
#define OUT_MASK 75497472ull
#define OUT_PRED 76283904ull

using short8 = __attribute__((ext_vector_type(8))) short;
using half8  = __attribute__((ext_vector_type(8))) _Float16;
using f32x4  = __attribute__((ext_vector_type(4))) float;
using float4v = __attribute__((ext_vector_type(4))) float;

__device__ __forceinline__ short f2h(float f) {
    _Float16 h = (_Float16)f;
    return __builtin_bit_cast(short, h);
}
__device__ __forceinline__ float h2f(short s) {
    _Float16 h = __builtin_bit_cast(_Float16, s);
    return (float)h;
}
__device__ __forceinline__ float ftanh(float x) {
    float ax = fabsf(x);
    float e = __expf(-2.0f * ax);
    float r = (1.0f - e) / (1.0f + e);
    return copysignf(r, x);
}

// ---------------------------------------------------------------------------
// k_pre: fused adj-histogram (blocks 0..47), weight transpose (48..303),
// mask + fp16 x / x_masked (304..1071). All parts independent.
// ---------------------------------------------------------------------------
__global__ void __launch_bounds__(256) k_pre(const int* __restrict__ ei,
                                             const float* __restrict__ x,
                                             const float* __restrict__ M,
                                             const float* __restrict__ Wa,
                                             const float* __restrict__ Wb,
                                             const float* __restrict__ Wc,
                                             float* __restrict__ out,
                                             short* __restrict__ adjT,
                                             unsigned char* __restrict__ a8,
                                             short* __restrict__ xh,
                                             short* __restrict__ xmh,
                                             short* __restrict__ WT)
{
    __shared__ unsigned int A[NPG_ * NPG_]; // 64 KB (adj blocks only)
    const int bid = blockIdx.x, t = threadIdx.x;
    if (bid < 48) {
        const int g = bid;
        for (int i = t; i < NPG_ * NPG_; i += 256) A[i] = 0u;
        __syncthreads();
        const int* srcp = ei + g * EPG_;
        const int* dstp = ei + ETOT_ + g * EPG_;
        const int base = g * NPG_;
        for (int i = t; i < EPG_; i += 256) {
            int s = srcp[i] - base;
            int d = dstp[i] - base;
            atomicAdd(&A[s * NPG_ + d], 1u);
        }
        __syncthreads();
        for (int i = t; i < NPG_ * NPG_; i += 256) {
            int r = i >> 7, c = i & 127;
            unsigned int cnt = A[i];
            out[OUT_ADJ + (size_t)(base + r) * NTOT_ + base + c] = (float)cnt;
            adjT[g * NPG_ * NPG_ + c * NPG_ + r] = f2h((float)cnt); // exact small ints
            a8[g * NPG_ * NPG_ + i] = (unsigned char)cnt;
        }
    } else if (bid < 304) {
        const int wtb = bid - 48;
        #pragma unroll
        for (int e = 0; e < 4; e++) {
            int idx = wtb * 1024 + e * 256 + t;
            if (idx < 65536) {                       // WaT[l][n<256][k<128] = Wa[l][k][n]
                int l = idx >> 15, r = idx & 32767;
                int n = r >> 7, k = r & 127;
                WT[idx] = f2h(Wa[l * 32768 + k * 256 + n]);
            } else if (idx < 196608) {               // WbT[l][n<256][k<256] = Wb[l][k][n]
                int j = idx - 65536;
                int l = j >> 16, r = j & 65535;
                int n = r >> 8, k = r & 255;
                WT[idx] = f2h(Wb[l * 65536 + k * 256 + n]);
            } else {                                 // WcT[l][n<128][k<256] = Wc[l][k][n]
                int j = idx - 196608;
                int l = j >> 15, r = j & 32767;
                int n = r >> 8, k = r & 255;
                WT[idx] = f2h(Wc[l * 32768 + k * 128 + n]);
            }
        }
    } else {
        int idx = (bid - 304) * 256 + t;             // < 196608
        float4v mv = *(const float4v*)(M + idx * 4);
        float4v xv = *(const float4v*)(x + idx * 4);
        float4v om;
        short hx[4], hm[4];
        #pragma unroll
        for (int e = 0; e < 4; e++) {
            bool pos = (mv[e] > 0.0f);
            om[e] = pos ? 1.0f : 0.0f;
            hx[e] = f2h(xv[e]);
            hm[e] = pos ? hx[e] : (short)0;
        }
        *(float4v*)(out + OUT_MASK + idx * 4) = om;
        *(unsigned long long*)(xh + idx * 4)  = *(unsigned long long*)hx;
        *(unsigned long long*)(xmh + idx * 4) = *(unsigned long long*)hm;
    }
}

// ---------------------------------------------------------------------------
// Perturbed adjacency: S = P_g @ A_g + Bp_g accumulated in f64 (sign-exact);
// pert_adj = (S > 0). Writes f32 0/1 diag block + fp16 transposed copy.
// ---------------------------------------------------------------------------
__global__ void __launch_bounds__(256) k_pert(const float* __restrict__ P,
                                              const float* __restrict__ Bp,
                                              const unsigned char* __restrict__ a8,
                                              float* __restrict__ out1,
                                              short* __restrict__ pertT)
{
    __shared__ unsigned char sA[NPG_ * NPG_]; // 16 KB, [k][j]
    const int g = blockIdx.x >> 3;
    const int i0 = (blockIdx.x & 7) * 16;
    const int t = threadIdx.x;
    const unsigned char* a = a8 + g * NPG_ * NPG_;
    for (int i = t * 4; i < NPG_ * NPG_; i += 1024)
        *(unsigned int*)&sA[i] = *(const unsigned int*)(a + i);
    __syncthreads();
    const int i = i0 + (t >> 4);
    const int j0 = (t & 15) * 8;
    const float* Prow = P + ((size_t)g * NPG_ + i) * NPG_;
    const float* Brow = Bp + ((size_t)g * NPG_ + i) * NPG_ + j0;
    double acc[8];
    #pragma unroll
    for (int jj = 0; jj < 8; jj++) acc[jj] = (double)Brow[jj];
    for (int k = 0; k < NPG_; k++) {
        double p = (double)Prow[k];
        const unsigned char* ar = &sA[k * NPG_ + j0];
        #pragma unroll
        for (int jj = 0; jj < 8; jj++) acc[jj] += p * (double)ar[jj];
    }
    const size_t obase = (size_t)(g * NPG_ + i) * NTOT_ + g * NPG_ + j0;
    #pragma unroll
    for (int jj = 0; jj < 8; jj++) {
        bool one = (acc[jj] > 0.0);
        out1[obase + jj] = one ? 1.0f : 0.0f;
        pertT[g * NPG_ * NPG_ + (j0 + jj) * NPG_ + i] = one ? (short)0x3C00 : (short)0;
    }
}

// ---------------------------------------------------------------------------
// GIN helpers. LDS map (shorts):
//   T0 [0,16384)      : hT (128 feat x 128 node, swizzled)  / fc out rows
//   T1 [16384,32768)  : z tile / fc out rows
//   W  [32768,65536)  : staged weight panel (64 KB), col-swizzled
// fc tiles 128x256 span T0∪T1 (in-place, A-regs + barrier discipline).
// Swizzle everywhere: elem_idx ^= (row&7)<<3 on the contiguous dim.
// ---------------------------------------------------------------------------
template<int KROW> // shorts per weight column (K of the phase)
__device__ __forceinline__ void stage_w(short* S, const short* __restrict__ src, int t)
{
    for (int i = t; i < 4096; i += 512) {
        short8 v = *(const short8*)(src + i * 8);
        int col = (i * 8) / KROW;
        int k0  = (i * 8) % KROW;
        *(short8*)&S[32768 + col * KROW + (k0 ^ ((col & 7) << 3))] = v;
    }
}

template<int KS>
__device__ __forceinline__ void load_a(const short* S, int aoff, int lda, int arow, int lh, short8* a)
{
    #pragma unroll
    for (int ks = 0; ks < KS; ks++)
        a[ks] = *(const short8*)&S[aoff + arow * lda + ((ks * 32 + lh * 8) ^ ((arow & 7) << 3))];
}

template<int KS, int MODE>
__device__ __forceinline__ void fc_compute(short* S, const short8* a, int outoff, int ldo,
                                           const float* __restrict__ bias,
                                           int ntLo, int ntHi, int wcol0,
                                           int w, int lr, int lh)
{
    const int KROW = KS * 32;
    for (int nt = ntLo; nt < ntHi; nt++) {
        int col = nt * 16 + lr;
        f32x4 acc = {0.f, 0.f, 0.f, 0.f};
        #pragma unroll
        for (int ks = 0; ks < KS; ks++) {
            half8 b = __builtin_bit_cast(half8,
                *(const short8*)&S[32768 + (col - wcol0) * KROW + ((ks * 32 + lh * 8) ^ ((col & 7) << 3))]);
            acc = __builtin_amdgcn_mfma_f32_16x16x32_f16(__builtin_bit_cast(half8, a[ks]), b, acc, 0, 0, 0);
        }
        float bv = bias[col];
        #pragma unroll
        for (int r = 0; r < 4; r++) {
            int row = w * 16 + lh * 4 + r;
            float v = ftanh(acc[r] + bv);
            if (MODE == 0) {
                S[outoff + row * ldo + (col ^ ((row & 7) << 3))] = f2h(v);
            } else {
                float th = ftanh(v);                  // GNN outer tanh
                S[col * 128 + (row ^ ((col & 7) << 3))] = f2h(th); // new hT
            }
        }
    }
}

// ---------------------------------------------------------------------------
// k_main: blocks 0..143 = fused GIN; blocks 144..3215 = off-diagonal
// zero-fill of the two NxN maps (nontemporal dwordx4). Fill overlaps GIN.
// ---------------------------------------------------------------------------
__global__ void __launch_bounds__(512) k_main(
    const short* __restrict__ xh, const short* __restrict__ xmh,
    const short* __restrict__ adjT, const short* __restrict__ pertT,
    const short* __restrict__ WT,
    const float* __restrict__ ba, const float* __restrict__ bb, const float* __restrict__ bc,
    const float* __restrict__ mW1, const float* __restrict__ mb1,
    const float* __restrict__ mW2, const float* __restrict__ mb2,
    const float* __restrict__ mW3, const float* __restrict__ mb3,
    float* __restrict__ out)
{
    __shared__ short S[65536]; // 128 KB
    __shared__ float aux[160];
    const int bid = blockIdx.x;
    const int t = threadIdx.x;

    if (bid >= 144) {
        // ---- zero-fill: 4 rows per block, 2 maps x 6144 rows, skip diag block
        const int fid = bid - 144;                   // [0,3072)
        float4v* p = (float4v*)out;
        const float4v z = {0.f, 0.f, 0.f, 0.f};
        #pragma unroll
        for (int q = 0; q < 4; q++) {
            int cr = fid * 4 + q;                    // [0,12288)
            int m  = cr >= 6144;
            int r  = cr - (m ? 6144 : 0);
            int gr = r >> 7;
            size_t base4 = ((m ? OUT_PERT : OUT_ADJ) >> 2) + (size_t)r * 1536;
            int dlo = gr * 32, dhi = dlo + 32;
            #pragma unroll
            for (int it = 0; it < 3; it++) {
                int s = it * 512 + t;
                if (s < dlo || s >= dhi)
                    __builtin_nontemporal_store(z, p + base4 + s);
            }
        }
        return;
    }

    // ---- GIN part
    const int run = bid % 3, g = bid / 3;
    const int w = t >> 6, l = t & 63, lr = l & 15, lh = l >> 4;
    const int arow = w * 16 + lr;

    const short* h0 = (run == 2 ? xmh : xh) + g * NPG_ * D_;
    const short* am = (run == 1 ? pertT : adjT) + g * NPG_ * NPG_;

    // hT init: hT[d][s] = x[s][d], swizzled within row d
    for (int i = t; i < NPG_ * D_ / 8; i += 512) {
        short8 v = *(const short8*)(h0 + i * 8);
        int s0 = i >> 4, d0 = (i & 15) * 8;
        #pragma unroll
        for (int e = 0; e < 8; e++) {
            int d = d0 + e;
            S[d * 128 + (s0 ^ ((d & 7) << 3))] = v[e];
        }
    }
    __syncthreads();

    for (int layer = 0; layer < 2; layer++) {
        const short* WaT = WT + layer * 32768;
        const short* WbT = WT + 65536 + layer * 65536;
        const short* WcT = WT + 196608 + layer * 32768;
        const float* baL = ba + layer * 256;
        const float* bbL = bb + layer * 256;
        const float* bcL = bc + layer * 128;

        // ---- p1: z = h + A^T h  (A = adjT/pertT rows from global, B = hT)
        {
            short8 a[4];
            #pragma unroll
            for (int ks = 0; ks < 4; ks++)
                a[ks] = *(const short8*)(am + arow * 128 + ks * 32 + lh * 8);
            for (int nt = 0; nt < 8; nt++) {
                int col = nt * 16 + lr;
                f32x4 acc = {0.f, 0.f, 0.f, 0.f};
                #pragma unroll
                for (int ks = 0; ks < 4; ks++) {
                    half8 b = __builtin_bit_cast(half8,
                        *(const short8*)&S[col * 128 + ((ks * 32 + lh * 8) ^ ((col & 7) << 3))]);
                    acc = __builtin_amdgcn_mfma_f32_16x16x32_f16(__builtin_bit_cast(half8, a[ks]), b, acc, 0, 0, 0);
                }
                #pragma unroll
                for (int r = 0; r < 4; r++) {
                    int row = w * 16 + lh * 4 + r;
                    float hv = h2f(S[col * 128 + (row ^ ((col & 7) << 3))]); // h[row][col]
                    S[16384 + row * 128 + (col ^ ((row & 7) << 3))] = f2h(hv + acc[r]);
                }
            }
        }
        __syncthreads();

        // ---- fc1: t1(128x256) = tanh(z @ Wa + ba), out over T0∪T1
        {
            short8 a[4];
            load_a<4>(S, 16384, 128, arow, lh, a);
            stage_w<128>(S, WaT, t);
            __syncthreads();
            fc_compute<4, 0>(S, a, 0, 256, baL, 0, 16, 0, w, lr, lh);
        }
        __syncthreads();

        // ---- fc2: t2 = tanh(t1 @ Wb + bb), in place, W staged in 2 halves
        {
            short8 a[8];
            load_a<8>(S, 0, 256, arow, lh, a);
            stage_w<256>(S, WbT, t);                  // cols 0..127
            __syncthreads();
            fc_compute<8, 0>(S, a, 0, 256, bbL, 0, 8, 0, w, lr, lh);
            __syncthreads();
            stage_w<256>(S, WbT + 32768, t);          // cols 128..255
            __syncthreads();
            fc_compute<8, 0>(S, a, 0, 256, bbL, 8, 16, 128, w, lr, lh);
        }
        __syncthreads();

        // ---- fc3: h = tanh(tanh(t2 @ Wc + bc)) -> new hT in T0
        {
            short8 a[8];
            load_a<8>(S, 0, 256, arow, lh, a);
            stage_w<256>(S, WcT, t);
            __syncthreads();
            fc_compute<8, 1>(S, a, 0, 128, bcL, 0, 8, 0, w, lr, lh);
        }
        __syncthreads();
    }

    // mean-pool per feature from hT rows (rotated: any row permutation sums equal)
    if (t < 128) {
        float s = 0.f;
        for (int nn = 0; nn < 128; nn++)
            s += h2f(S[t * 128 + ((nn + t) & 127)]);
        aux[t] = s * 0.0078125f;
    }
    __syncthreads();
    if (t < 16) {
        float a = mb1[t];
        for (int d = 0; d < 128; d++) a += aux[d] * mW1[d * 16 + t];
        aux[128 + t] = ftanh(a);
    }
    __syncthreads();
    if (t < 8) {
        float a = mb2[t];
        #pragma unroll
        for (int d = 0; d < 16; d++) a += aux[128 + d] * mW2[d * 8 + t];
        aux[144 + t] = ftanh(a);
    }
    __syncthreads();
    if (t < 2) {
        float a = mb3[t];
        #pragma unroll
        for (int d = 0; d < 8; d++) a += aux[144 + d] * mW3[d * 2 + t];
        out[OUT_PRED + (size_t)run * 96 + g * 2 + t] = ftanh(a);
    }
}

// ---------------------------------------------------------------------------
extern "C" void kernel_launch(void* const* d_in, const int* in_sizes, int n_in,
                              void* d_out, int out_size, void* d_ws, size_t ws_size,
                              hipStream_t stream)
{
    (void)in_sizes; (void)n_in; (void)out_size; (void)ws_size;

    const float* x   = (const float*)d_in[0];
    const int*   ei  = (const int*)d_in[1];
    const float* P   = (const float*)d_in[3];
    const float* Bp  = (const float*)d_in[4];
    const float* M   = (const float*)d_in[5];
    const float* Wa  = (const float*)d_in[6];
    const float* ba  = (const float*)d_in[7];
    const float* Wb  = (const float*)d_in[8];
    const float* bb  = (const float*)d_in[9];
    const float* Wc  = (const float*)d_in[10];
    const float* bc  = (const float*)d_in[11];
    const float* mW1 = (const float*)d_in[12];
    const float* mb1 = (const float*)d_in[13];
    const float* mW2 = (const float*)d_in[14];
    const float* mb2 = (const float*)d_in[15];
    const float* mW3 = (const float*)d_in[16];
    const float* mb3 = (const float*)d_in[17];
    float* out = (float*)d_out;

    char* ws = (char*)d_ws;
    short*         adjT  = (short*)(ws + 0);        // 1,572,864 B
    short*         pertT = (short*)(ws + 1572864);  // 1,572,864 B
    unsigned char* a8    = (unsigned char*)(ws + 3145728); // 786,432 B
    short*         xhp   = (short*)(ws + 3932160);  // 1,572,864 B
    short*         xmh   = (short*)(ws + 5505024);  // 1,572,864 B
    short*         WT    = (short*)(ws + 7077888);  // 524,288 B

    k_pre <<<1072, 256, 0, stream>>>(ei, x, M, Wa, Wb, Wc, out, adjT, a8, xhp, xmh, WT);
    k_pert<<<384,  256, 0, stream>>>(P, Bp, a8, out + OUT_PERT, pertT);
    k_main<<<3216, 512, 0, stream>>>(xhp, xmh, adjT, pertT, WT, ba, bb, bc,
                                     mW1, mb1, mW2, mb2, mW3, mb3, out);
}

// Round 6
// 165.668 us; speedup vs baseline: 1.1975x; 1.1975x over previous
//
#include <hip/hip_runtime.h>

#define G_    48
#define NPG_  128
#define NTOT_ 6144
#define D_    128
#define EPG_  4096
#define ETOT_ 196608

// element offsets into f32 d_out
#define OUT_ADJ  0ull
#define OUT_PERT 37748736ull
#define OUT_MASK 75497472ull
#define OUT_PRED 76283904ull

using short8 = __attribute__((ext_vector_type(8))) short;
using short4v = __attribute__((ext_vector_type(4))) short;
using half8  = __attribute__((ext_vector_type(8))) _Float16;
using f32x4  = __attribute__((ext_vector_type(4))) float;
using float4v = __attribute__((ext_vector_type(4))) float;

__device__ __forceinline__ short f2h(float f) {
    _Float16 h = (_Float16)f;
    return __builtin_bit_cast(short, h);
}
__device__ __forceinline__ float h2f(short s) {
    _Float16 h = __builtin_bit_cast(_Float16, s);
    return (float)h;
}
__device__ __forceinline__ float ftanh(float x) {
    float ax = fabsf(x);
    float e = __expf(-2.0f * ax);
    float r = (1.0f - e) / (1.0f + e);
    return copysignf(r, x);
}

// ---------------------------------------------------------------------------
// k_pre: blocks 0..47 adj histogram; 48..303 weight transpose;
// 304..399 mask + fp16 transposed x / x_masked (xhT/xmhT, [g][feat][node]).
// ---------------------------------------------------------------------------
__global__ void __launch_bounds__(256) k_pre(const int* __restrict__ ei,
                                             const float* __restrict__ x,
                                             const float* __restrict__ M,
                                             const float* __restrict__ Wa,
                                             const float* __restrict__ Wb,
                                             const float* __restrict__ Wc,
                                             float* __restrict__ out,
                                             short* __restrict__ adjT,
                                             unsigned char* __restrict__ a8,
                                             short* __restrict__ xhT,
                                             short* __restrict__ xmhT,
                                             short* __restrict__ WT)
{
    __shared__ char sm[65536];
    const int bid = blockIdx.x, t = threadIdx.x;
    if (bid < 48) {
        unsigned int* A = (unsigned int*)sm;         // [128][128]
        const int g = bid;
        for (int i = t; i < NPG_ * NPG_; i += 256) A[i] = 0u;
        __syncthreads();
        const int* srcp = ei + g * EPG_;
        const int* dstp = ei + ETOT_ + g * EPG_;
        const int base = g * NPG_;
        for (int i = t; i < EPG_; i += 256) {
            int s = srcp[i] - base;
            int d = dstp[i] - base;
            atomicAdd(&A[s * NPG_ + d], 1u);
        }
        __syncthreads();
        for (int i = t; i < NPG_ * NPG_; i += 256) {
            int r = i >> 7, c = i & 127;
            unsigned int cnt = A[i];
            out[OUT_ADJ + (size_t)(base + r) * NTOT_ + base + c] = (float)cnt;
            adjT[g * NPG_ * NPG_ + c * NPG_ + r] = f2h((float)cnt); // exact small ints
            a8[g * NPG_ * NPG_ + i] = (unsigned char)cnt;
        }
    } else if (bid < 304) {
        const int wtb = bid - 48;
        #pragma unroll
        for (int e = 0; e < 4; e++) {
            int idx = wtb * 1024 + e * 256 + t;
            if (idx < 65536) {                       // WaT[l][n<256][k<128] = Wa[l][k][n]
                int l = idx >> 15, r = idx & 32767;
                int n = r >> 7, k = r & 127;
                WT[idx] = f2h(Wa[l * 32768 + k * 256 + n]);
            } else if (idx < 196608) {               // WbT[l][n<256][k<256] = Wb[l][k][n]
                int j = idx - 65536;
                int l = j >> 16, r = j & 65535;
                int n = r >> 8, k = r & 255;
                WT[idx] = f2h(Wb[l * 65536 + k * 256 + n]);
            } else {                                 // WcT[l][n<128][k<256] = Wc[l][k][n]
                int j = idx - 196608;
                int l = j >> 15, r = j & 32767;
                int n = r >> 8, k = r & 255;
                WT[idx] = f2h(Wc[l * 32768 + k * 128 + n]);
            }
        }
    } else {
        // mask + transpose: 2 blocks per graph, 64 nodes each
        short* sT  = (short*)sm;                     // [128 f][64 s]
        short* sTm = (short*)sm + 8192;
        const int b2 = bid - 304;
        const int g = b2 >> 1, half = b2 & 1;
        const size_t n0 = (size_t)g * 128 + half * 64;
        const float* xb = x + n0 * 128;
        const float* Mb = M + n0 * 128;
        float* om = out + OUT_MASK + n0 * 128;
        #pragma unroll
        for (int j = 0; j < 8; j++) {
            int i = j * 256 + t;                     // 2048 float4s = 64x128
            float4v xv = *(const float4v*)(xb + i * 4);
            float4v mv = *(const float4v*)(Mb + i * 4);
            int nl = i >> 5;                         // local node
            int f0 = (i & 31) * 4;
            float4v o;
            #pragma unroll
            for (int e = 0; e < 4; e++) {
                bool pos = (mv[e] > 0.0f);
                o[e] = pos ? 1.0f : 0.0f;
                short hx = f2h(xv[e]);
                sT [(f0 + e) * 64 + nl] = hx;
                sTm[(f0 + e) * 64 + nl] = pos ? hx : (short)0;
            }
            *(float4v*)(om + i * 4) = o;
        }
        __syncthreads();
        short* dx  = xhT  + (size_t)g * 16384 + half * 64;
        short* dxm = xmhT + (size_t)g * 16384 + half * 64;
        int f = t >> 1, c0 = (t & 1) * 32;
        #pragma unroll
        for (int k = 0; k < 4; k++) {
            *(short8*)(dx  + f * 128 + c0 + k * 8) = *(short8*)&sT [f * 64 + c0 + k * 8];
            *(short8*)(dxm + f * 128 + c0 + k * 8) = *(short8*)&sTm[f * 64 + c0 + k * 8];
        }
    }
}

// ---------------------------------------------------------------------------
// k_pert: S = P_g @ A_g + Bp_g in f64 (sign-exact); pert_adj = (S > 0).
// ---------------------------------------------------------------------------
__global__ void __launch_bounds__(256) k_pert(const float* __restrict__ P,
                                              const float* __restrict__ Bp,
                                              const unsigned char* __restrict__ a8,
                                              float* __restrict__ out1,
                                              short* __restrict__ pertT)
{
    __shared__ unsigned char sA[NPG_ * NPG_]; // 16 KB, [k][j]
    const int g = blockIdx.x >> 3;
    const int i0 = (blockIdx.x & 7) * 16;
    const int t = threadIdx.x;
    const unsigned char* a = a8 + g * NPG_ * NPG_;
    for (int i = t * 4; i < NPG_ * NPG_; i += 1024)
        *(unsigned int*)&sA[i] = *(const unsigned int*)(a + i);
    __syncthreads();
    const int i = i0 + (t >> 4);
    const int j0 = (t & 15) * 8;
    const float* Prow = P + ((size_t)g * NPG_ + i) * NPG_;
    const float* Brow = Bp + ((size_t)g * NPG_ + i) * NPG_ + j0;
    double acc[8];
    #pragma unroll
    for (int jj = 0; jj < 8; jj++) acc[jj] = (double)Brow[jj];
    for (int k = 0; k < NPG_; k++) {
        double p = (double)Prow[k];
        const unsigned char* ar = &sA[k * NPG_ + j0];
        #pragma unroll
        for (int jj = 0; jj < 8; jj++) acc[jj] += p * (double)ar[jj];
    }
    const size_t obase = (size_t)(g * NPG_ + i) * NTOT_ + g * NPG_ + j0;
    #pragma unroll
    for (int jj = 0; jj < 8; jj++) {
        bool one = (acc[jj] > 0.0);
        out1[obase + jj] = one ? 1.0f : 0.0f;
        pertT[g * NPG_ * NPG_ + (j0 + jj) * NPG_ + i] = one ? (short)0x3C00 : (short)0;
    }
}

// ---------------------------------------------------------------------------
// k_layer<L>: one GIN layer for all 144 (g,run) tiles, 4 row-blocks each
// (576 compute blocks, 32 rows per block, 4 waves: 2 row-strips x 2 col-halves).
// Blocks 576.. : zero-fill of one NxN map (6144 rows, 4 rows/block).
// LDS (shorts): hT [0,16384) staged swizzled; z [16384,20480); t [16384,24576).
// MFMA 16x16x32_f16; swizzle: idx ^= (row&7)<<3 on the contiguous dim.
// ---------------------------------------------------------------------------
template<int LAYER>
__global__ void __launch_bounds__(256) k_layer(
    const short* __restrict__ hTx, const short* __restrict__ hTxm,
    const short* __restrict__ hTprev,
    const short* __restrict__ adjT, const short* __restrict__ pertT,
    const short* __restrict__ WT,
    const float* __restrict__ ba, const float* __restrict__ bb, const float* __restrict__ bc,
    short* __restrict__ hTout,
    float* __restrict__ out, long fillRowBase)
{
    __shared__ short S[24576]; // 48 KB
    const int bid = blockIdx.x, t = threadIdx.x;

    if (bid >= 576) {
        // ---- zero-fill 4 rows of a NxN map, skipping the diagonal block
        const int fid = bid - 576;                   // [0,1536)
        float4v* p = (float4v*)out;
        const float4v z4 = {0.f, 0.f, 0.f, 0.f};
        #pragma unroll
        for (int q = 0; q < 4; q++) {
            long r = fillRowBase + (long)fid * 4 + q;   // virtual row [0,12288)
            long rr = (r >= 6144) ? r - 6144 : r;
            size_t base4 = ((r >= 6144) ? (OUT_PERT >> 2) : 0) + (size_t)rr * 1536;
            int gr = (int)(rr >> 7);
            int dlo = gr * 32, dhi = dlo + 32;
            #pragma unroll
            for (int it = 0; it < 6; it++) {
                int s = it * 256 + t;
                if (s < dlo || s >= dhi)
                    __builtin_nontemporal_store(z4, p + base4 + s);
            }
        }
        return;
    }

    const int tile = bid >> 2, rs = bid & 3;
    const int run = tile % 3, g = tile / 3;
    const int w = t >> 6, l = t & 63, lr = l & 15, lh = l >> 4;
    const int sl = (w >> 1) * 16;                    // strip within block's 32 rows
    const int ch = w & 1;                            // column half
    const int rowg0 = rs * 32;

    const short* hin = (LAYER == 0)
        ? ((run == 2 ? hTxm : hTx) + (size_t)g * 16384)
        : (hTprev + (size_t)tile * 16384);
    const short* am = (run == 1 ? pertT : adjT) + (size_t)g * 16384;
    const short* WaT = WT + LAYER * 32768;
    const short* WbT = WT + 65536 + LAYER * 65536;
    const short* WcT = WT + 196608 + LAYER * 32768;
    const float* baL = ba + LAYER * 256;
    const float* bbL = bb + LAYER * 256;
    const float* bcL = bc + LAYER * 128;

    // ---- stage hT (swizzled)
    #pragma unroll
    for (int j = 0; j < 8; j++) {
        int i = j * 256 + t;
        int f = i >> 4, s0 = (i & 15) * 8;
        short8 v = *(const short8*)(hin + f * 128 + s0);
        *(short8*)&S[f * 128 + (s0 ^ ((f & 7) << 3))] = v;
    }
    __syncthreads();

    // ---- p1: z = h + A^T h  (rows = this block's strip, cols = 128 features)
    {
        const int ar = rowg0 + sl + lr;
        short8 a0 = *(const short8*)(am + ar * 128 +   0 + lh * 8);
        short8 a1 = *(const short8*)(am + ar * 128 +  32 + lh * 8);
        short8 a2 = *(const short8*)(am + ar * 128 +  64 + lh * 8);
        short8 a3 = *(const short8*)(am + ar * 128 +  96 + lh * 8);
        #pragma unroll
        for (int nt = 0; nt < 4; nt++) {
            int col = ch * 64 + nt * 16 + lr;
            f32x4 acc = {0.f, 0.f, 0.f, 0.f};
            half8 b;
            b = __builtin_bit_cast(half8, *(const short8*)&S[col * 128 + ((  0 + lh * 8) ^ ((col & 7) << 3))]);
            acc = __builtin_amdgcn_mfma_f32_16x16x32_f16(__builtin_bit_cast(half8, a0), b, acc, 0, 0, 0);
            b = __builtin_bit_cast(half8, *(const short8*)&S[col * 128 + (( 32 + lh * 8) ^ ((col & 7) << 3))]);
            acc = __builtin_amdgcn_mfma_f32_16x16x32_f16(__builtin_bit_cast(half8, a1), b, acc, 0, 0, 0);
            b = __builtin_bit_cast(half8, *(const short8*)&S[col * 128 + (( 64 + lh * 8) ^ ((col & 7) << 3))]);
            acc = __builtin_amdgcn_mfma_f32_16x16x32_f16(__builtin_bit_cast(half8, a2), b, acc, 0, 0, 0);
            b = __builtin_bit_cast(half8, *(const short8*)&S[col * 128 + (( 96 + lh * 8) ^ ((col & 7) << 3))]);
            acc = __builtin_amdgcn_mfma_f32_16x16x32_f16(__builtin_bit_cast(half8, a3), b, acc, 0, 0, 0);
            #pragma unroll
            for (int r = 0; r < 4; r++) {
                int zl = sl + lh * 4 + r;
                int rg = rowg0 + zl;
                float hv = h2f(S[col * 128 + (rg ^ ((col & 7) << 3))]);
                S[16384 + zl * 128 + (col ^ ((zl & 7) << 3))] = f2h(hv + acc[r]);
            }
        }
    }
    __syncthreads();

    // ---- fc1: t1(32x256) = tanh(z @ Wa + ba)   (K=128, B from global)
    {
        const int za = sl + lr;
        short8 a0 = *(const short8*)&S[16384 + za * 128 + ((  0 + lh * 8) ^ ((za & 7) << 3))];
        short8 a1 = *(const short8*)&S[16384 + za * 128 + (( 32 + lh * 8) ^ ((za & 7) << 3))];
        short8 a2 = *(const short8*)&S[16384 + za * 128 + (( 64 + lh * 8) ^ ((za & 7) << 3))];
        short8 a3 = *(const short8*)&S[16384 + za * 128 + (( 96 + lh * 8) ^ ((za & 7) << 3))];
        __syncthreads();                              // t1 overlaps z
        #pragma unroll 4
        for (int nt = 0; nt < 8; nt++) {
            int col = ch * 128 + nt * 16 + lr;
            const short* wb = WaT + col * 128 + lh * 8;
            f32x4 acc = {0.f, 0.f, 0.f, 0.f};
            half8 b;
            b = __builtin_bit_cast(half8, *(const short8*)(wb +   0));
            acc = __builtin_amdgcn_mfma_f32_16x16x32_f16(__builtin_bit_cast(half8, a0), b, acc, 0, 0, 0);
            b = __builtin_bit_cast(half8, *(const short8*)(wb +  32));
            acc = __builtin_amdgcn_mfma_f32_16x16x32_f16(__builtin_bit_cast(half8, a1), b, acc, 0, 0, 0);
            b = __builtin_bit_cast(half8, *(const short8*)(wb +  64));
            acc = __builtin_amdgcn_mfma_f32_16x16x32_f16(__builtin_bit_cast(half8, a2), b, acc, 0, 0, 0);
            b = __builtin_bit_cast(half8, *(const short8*)(wb +  96));
            acc = __builtin_amdgcn_mfma_f32_16x16x32_f16(__builtin_bit_cast(half8, a3), b, acc, 0, 0, 0);
            float bv = baL[col];
            #pragma unroll
            for (int r = 0; r < 4; r++) {
                int zl = sl + lh * 4 + r;
                S[16384 + zl * 256 + (col ^ ((zl & 7) << 3))] = f2h(ftanh(acc[r] + bv));
            }
        }
    }
    __syncthreads();

    // ---- fc2: t2 = tanh(t1 @ Wb + bb)  (K=256, in place over t1)
    {
        const int za = sl + lr;
        short8 a[8];
        #pragma unroll
        for (int ks = 0; ks < 8; ks++)
            a[ks] = *(const short8*)&S[16384 + za * 256 + ((ks * 32 + lh * 8) ^ ((za & 7) << 3))];
        __syncthreads();                              // in-place
        #pragma unroll 4
        for (int nt = 0; nt < 8; nt++) {
            int col = ch * 128 + nt * 16 + lr;
            const short* wb = WbT + col * 256 + lh * 8;
            f32x4 acc = {0.f, 0.f, 0.f, 0.f};
            #pragma unroll
            for (int ks = 0; ks < 8; ks++) {
                half8 b = __builtin_bit_cast(half8, *(const short8*)(wb + ks * 32));
                acc = __builtin_amdgcn_mfma_f32_16x16x32_f16(__builtin_bit_cast(half8, a[ks]), b, acc, 0, 0, 0);
            }
            float bv = bbL[col];
            #pragma unroll
            for (int r = 0; r < 4; r++) {
                int zl = sl + lh * 4 + r;
                S[16384 + zl * 256 + (col ^ ((zl & 7) << 3))] = f2h(ftanh(acc[r] + bv));
            }
        }
    }
    __syncthreads();

    // ---- fc3: h' = tanh(tanh(t2 @ Wc + bc)) -> global hTout (feature-major)
    {
        const int za = sl + lr;
        short8 a[8];
        #pragma unroll
        for (int ks = 0; ks < 8; ks++)
            a[ks] = *(const short8*)&S[16384 + za * 256 + ((ks * 32 + lh * 8) ^ ((za & 7) << 3))];
        #pragma unroll
        for (int nt = 0; nt < 4; nt++) {
            int col = ch * 64 + nt * 16 + lr;
            const short* wb = WcT + col * 256 + lh * 8;
            f32x4 acc = {0.f, 0.f, 0.f, 0.f};
            #pragma unroll
            for (int ks = 0; ks < 8; ks++) {
                half8 b = __builtin_bit_cast(half8, *(const short8*)(wb + ks * 32));
                acc = __builtin_amdgcn_mfma_f32_16x16x32_f16(__builtin_bit_cast(half8, a[ks]), b, acc, 0, 0, 0);
            }
            float bv = bcL[col];
            short4v hv;
            #pragma unroll
            for (int r = 0; r < 4; r++)
                hv[r] = f2h(ftanh(ftanh(acc[r] + bv)));
            *(short4v*)(hTout + (size_t)tile * 16384 + col * 128 + rowg0 + sl + lh * 4) = hv;
        }
    }
}

// ---------------------------------------------------------------------------
// k_post: mean-pool (exact /128) + 3-layer MLP per (g,run). 144 blocks.
// ---------------------------------------------------------------------------
__global__ void __launch_bounds__(128) k_post(
    const short* __restrict__ hT2,
    const float* __restrict__ mW1, const float* __restrict__ mb1,
    const float* __restrict__ mW2, const float* __restrict__ mb2,
    const float* __restrict__ mW3, const float* __restrict__ mb3,
    float* __restrict__ out)
{
    __shared__ float aux[160];
    const int tile = blockIdx.x, t = threadIdx.x;
    const int run = tile % 3, g = tile / 3;
    const short* hp = hT2 + (size_t)tile * 16384 + t * 128;
    float s = 0.f;
    #pragma unroll 4
    for (int j = 0; j < 16; j++) {
        short8 v = *(const short8*)(hp + j * 8);
        #pragma unroll
        for (int e = 0; e < 8; e++) s += h2f(v[e]);
    }
    aux[t] = s * 0.0078125f;
    __syncthreads();
    if (t < 16) {
        float a = mb1[t];
        #pragma unroll 8
        for (int d = 0; d < 128; d++) a += aux[d] * mW1[d * 16 + t];
        aux[128 + t] = ftanh(a);
    }
    __syncthreads();
    if (t < 8) {
        float a = mb2[t];
        #pragma unroll
        for (int d = 0; d < 16; d++) a += aux[128 + d] * mW2[d * 8 + t];
        aux[144 + t] = ftanh(a);
    }
    __syncthreads();
    if (t < 2) {
        float a = mb3[t];
        #pragma unroll
        for (int d = 0; d < 8; d++) a += aux[144 + d] * mW3[d * 2 + t];
        out[OUT_PRED + (size_t)run * 96 + g * 2 + t] = ftanh(a);
    }
}

// ---------------------------------------------------------------------------
extern "C" void kernel_launch(void* const* d_in, const int* in_sizes, int n_in,
                              void* d_out, int out_size, void* d_ws, size_t ws_size,
                              hipStream_t stream)
{
    (void)in_sizes; (void)n_in; (void)out_size; (void)ws_size;

    const float* x   = (const float*)d_in[0];
    const int*   ei  = (const int*)d_in[1];
    const float* P   = (const float*)d_in[3];
    const float* Bp  = (const float*)d_in[4];
    const float* M   = (const float*)d_in[5];
    const float* Wa  = (const float*)d_in[6];
    const float* ba  = (const float*)d_in[7];
    const float* Wb  = (const float*)d_in[8];
    const float* bb  = (const float*)d_in[9];
    const float* Wc  = (const float*)d_in[10];
    const float* bc  = (const float*)d_in[11];
    const float* mW1 = (const float*)d_in[12];
    const float* mb1 = (const float*)d_in[13];
    const float* mW2 = (const float*)d_in[14];
    const float* mb2 = (const float*)d_in[15];
    const float* mW3 = (const float*)d_in[16];
    const float* mb3 = (const float*)d_in[17];
    float* out = (float*)d_out;

    char* ws = (char*)d_ws;
    short*         adjT  = (short*)(ws + 0);         // 1,572,864
    short*         pertT = (short*)(ws + 1572864);   // 1,572,864
    unsigned char* a8    = (unsigned char*)(ws + 3145728);  // 786,432
    short*         xhT   = (short*)(ws + 3932160);   // 1,572,864
    short*         xmhT  = (short*)(ws + 5505024);   // 1,572,864
    short*         WT    = (short*)(ws + 7077888);   // 524,288
    short*         hT1   = (short*)(ws + 7602176);   // 4,718,592
    short*         hT2   = (short*)(ws + 12320768);  // 4,718,592

    k_pre <<<400, 256, 0, stream>>>(ei, x, M, Wa, Wb, Wc, out, adjT, a8, xhT, xmhT, WT);
    k_pert<<<384, 256, 0, stream>>>(P, Bp, a8, out + OUT_PERT, pertT);
    k_layer<0><<<2112, 256, 0, stream>>>(xhT, xmhT, (const short*)nullptr,
                                         adjT, pertT, WT, ba, bb, bc, hT1, out, 0L);
    k_layer<1><<<2112, 256, 0, stream>>>(xhT, xmhT, hT1,
                                         adjT, pertT, WT, ba, bb, bc, hT2, out, 6144L);
    k_post<<<144, 128, 0, stream>>>(hT2, mW1, mb1, mW2, mb2, mW3, mb3, out);
}